// Round 1
// baseline (6029.760 us; speedup 1.0000x reference)
//
#include <hip/hip_runtime.h>
#include <math.h>

#define N_NODES 100000
#define N_EDGES 1600000
#define IN_CH 512
#define HID 128
#define OUT_CH 64

__device__ __forceinline__ float gelu_exact(float v) {
    return 0.5f * v * (1.0f + erff(v * 0.70710678118654752440f));
}

// ---------------- degree / norm ----------------
__global__ void deg_init(int* __restrict__ deg, int n) {
    int i = blockIdx.x * 256 + threadIdx.x;
    if (i < n) deg[i] = 1;  // self loop
}

__global__ void deg_count(const int* __restrict__ dst, int* __restrict__ deg, int e) {
    int i = blockIdx.x * 256 + threadIdx.x;
    if (i < e) atomicAdd(&deg[dst[i]], 1);
}

__global__ void dinv_k(const int* __restrict__ deg, float* __restrict__ dinv, int n) {
    int i = blockIdx.x * 256 + threadIdx.x;
    if (i < n) dinv[i] = rsqrtf((float)deg[i]);
}

// ---------------- generic tiled fp32 GEMM + bias (+gelu) ----------------
// C[M,BN] = A[M,K] @ B[K,BN] + bias ; block does 64 rows x BN cols
template <int BN, int TM, int TN, bool GELU>
__global__ __launch_bounds__(256) void gemm_bias_act(
    const float* __restrict__ A, const float* __restrict__ B,
    const float* __restrict__ bias, float* __restrict__ C, int M, int K) {
    const int BM = 64, BK = 16;
    __shared__ float As[BM][BK];
    __shared__ float Bs[BK][BN];
    const int tid = threadIdx.x;
    const int tx = tid % (BN / TN);
    const int ty = tid / (BN / TN);
    const int row0 = blockIdx.x * BM;

    float acc[TM][TN];
#pragma unroll
    for (int i = 0; i < TM; i++)
#pragma unroll
        for (int j = 0; j < TN; j++) acc[i][j] = 0.0f;

    const int aRow = tid >> 2;   // 0..63
    const int aQuad = tid & 3;   // 0..3 -> 4 floats each = BK
    const int bQuads = BK * BN / 4;

    for (int k0 = 0; k0 < K; k0 += BK) {
        float4 av = make_float4(0.f, 0.f, 0.f, 0.f);
        int gr = row0 + aRow;
        if (gr < M) av = *(const float4*)(A + (size_t)gr * K + k0 + aQuad * 4);
        *(float4*)(&As[aRow][aQuad * 4]) = av;
        const float4* bsrc = (const float4*)(B + (size_t)k0 * BN);
        float4* bdst = (float4*)(&Bs[0][0]);
#pragma unroll
        for (int i = tid; i < bQuads; i += 256) bdst[i] = bsrc[i];
        __syncthreads();
#pragma unroll
        for (int kk = 0; kk < BK; kk++) {
            float a[TM], b[TN];
#pragma unroll
            for (int i = 0; i < TM; i++) a[i] = As[ty * TM + i][kk];
#pragma unroll
            for (int j = 0; j < TN; j++) b[j] = Bs[kk][tx * TN + j];
#pragma unroll
            for (int i = 0; i < TM; i++)
#pragma unroll
                for (int j = 0; j < TN; j++) acc[i][j] += a[i] * b[j];
        }
        __syncthreads();
    }

#pragma unroll
    for (int i = 0; i < TM; i++) {
        int gr = row0 + ty * TM + i;
        if (gr >= M) continue;
        float4 v;
        float* vp = (float*)&v;
#pragma unroll
        for (int j = 0; j < TN; j++) {
            float c = acc[i][j] + bias[tx * TN + j];
            if (GELU) c = gelu_exact(c);
            vp[j] = c;
        }
        *(float4*)(C + (size_t)gr * BN + tx * TN) = v;
    }
}

// ---------------- rowwise LayerNorm over 128 ch (1 wave / row) ----------------
__global__ __launch_bounds__(256) void ln_k(float* __restrict__ h,
                                            const float* __restrict__ g,
                                            const float* __restrict__ be, int n) {
    int row = blockIdx.x * 4 + (threadIdx.x >> 6);
    int lane = threadIdx.x & 63;
    if (row >= n) return;
    float2 v = ((float2*)(h + (size_t)row * HID))[lane];
    float s = v.x + v.y;
    float sq = v.x * v.x + v.y * v.y;
#pragma unroll
    for (int o = 32; o > 0; o >>= 1) {
        s += __shfl_down(s, o);
        sq += __shfl_down(sq, o);
    }
    s = __shfl(s, 0);
    sq = __shfl(sq, 0);
    float mu = s * (1.0f / HID);
    float var = sq * (1.0f / HID) - mu * mu;
    float rs = rsqrtf(var + 1e-5f);
    float2 gv = ((const float2*)g)[lane];
    float2 bv = ((const float2*)be)[lane];
    v.x = (v.x - mu) * rs * gv.x + bv.x;
    v.y = (v.y - mu) * rs * gv.y + bv.y;
    ((float2*)(h + (size_t)row * HID))[lane] = v;
}

// ---------------- propagation ----------------
// self-loop term: out[i] = in[i] * dinv[i]^2   (plain store -> initializes out)
__global__ void prop_self(const float* __restrict__ hin, float* __restrict__ hout,
                          const float* __restrict__ dinv, int n) {
    int t = blockIdx.x * 256 + threadIdx.x;
    int i = t >> 5, c = t & 31;
    if (i >= n) return;
    float w = dinv[i];
    w = w * w;
    float4 v = ((const float4*)(hin + (size_t)i * HID))[c];
    v.x *= w; v.y *= w; v.z *= w; v.w *= w;
    ((float4*)(hout + (size_t)i * HID))[c] = v;
}

// edges: out[dst] += in[src] * dinv[src]*dinv[dst]; 32 threads per edge
__global__ void prop_edges(const float* __restrict__ hin, float* __restrict__ hout,
                           const int* __restrict__ src, const int* __restrict__ dst,
                           const float* __restrict__ dinv, int e) {
    int t = blockIdx.x * 256 + threadIdx.x;
    int ei = t >> 5, c = t & 31;
    if (ei >= e) return;
    int s = src[ei], d = dst[ei];
    float w = dinv[s] * dinv[d];
    float4 v = ((const float4*)(hin + (size_t)s * HID))[c];
    float* o = hout + (size_t)d * HID + c * 4;
    atomicAdd(o + 0, v.x * w);
    atomicAdd(o + 1, v.y * w);
    atomicAdd(o + 2, v.z * w);
    atomicAdd(o + 3, v.w * w);
}

extern "C" void kernel_launch(void* const* d_in, const int* in_sizes, int n_in,
                              void* d_out, int out_size, void* d_ws, size_t ws_size,
                              hipStream_t stream) {
    const float* x   = (const float*)d_in[0];
    const int*   ei  = (const int*)d_in[1];
    const float* W1  = (const float*)d_in[2];
    const float* b1  = (const float*)d_in[3];
    const float* g1  = (const float*)d_in[4];
    const float* be1 = (const float*)d_in[5];
    const float* Wc  = (const float*)d_in[6];
    const float* bc  = (const float*)d_in[7];
    const float* g2  = (const float*)d_in[8];
    const float* be2 = (const float*)d_in[9];
    const float* W2  = (const float*)d_in[10];
    const float* b2  = (const float*)d_in[11];
    float* out = (float*)d_out;

    const int N = in_sizes[0] / IN_CH;  // 100000
    const int E = in_sizes[1] / 2;      // 1600000
    const int* src = ei;
    const int* dst = ei + E;

    char* ws = (char*)d_ws;
    int* deg = (int*)ws;
    float* dinv = (float*)(ws + (((size_t)N * 4 + 255) & ~(size_t)255));
    float* bufA = (float*)(ws + (1u << 20));
    float* bufB = bufA + (size_t)N * HID;

    const int B = 256;
    // degrees + norm
    deg_init<<<(N + B - 1) / B, B, 0, stream>>>(deg, N);
    deg_count<<<(E + B - 1) / B, B, 0, stream>>>(dst, deg, E);
    dinv_k<<<(N + B - 1) / B, B, 0, stream>>>(deg, dinv, N);

    // lin1 + gelu -> bufA ; LN in place
    int gblk = (N + 63) / 64;
    gemm_bias_act<HID, 8, 4, true><<<gblk, B, 0, stream>>>(x, W1, b1, bufA, N, IN_CH);
    ln_k<<<(N + 3) / 4, B, 0, stream>>>(bufA, g1, be1, N);

    // hop 1: bufA -> bufB
    prop_self<<<((N * 32) + B - 1) / B, B, 0, stream>>>(bufA, bufB, dinv, N);
    prop_edges<<<((E * 32) + B - 1) / B, B, 0, stream>>>(bufA, bufB, src, dst, dinv, E);
    // hop 2: bufB -> bufA
    prop_self<<<((N * 32) + B - 1) / B, B, 0, stream>>>(bufB, bufA, dinv, N);
    prop_edges<<<((E * 32) + B - 1) / B, B, 0, stream>>>(bufB, bufA, src, dst, dinv, E);

    // Wc + gelu -> bufB ; LN in place
    gemm_bias_act<HID, 8, 4, true><<<gblk, B, 0, stream>>>(bufA, Wc, bc, bufB, N, HID);
    ln_k<<<(N + 3) / 4, B, 0, stream>>>(bufB, g2, be2, N);

    // W2 -> out
    gemm_bias_act<OUT_CH, 4, 4, false><<<gblk, B, 0, stream>>>(bufB, W2, b2, out, N, HID);
}

// Round 2
// 1035.164 us; speedup vs baseline: 5.8249x; 5.8249x over previous
//
#include <hip/hip_runtime.h>
#include <math.h>

#define N_NODES 100000
#define N_EDGES 1600000
#define IN_CH 512
#define HID 128
#define OUT_CH 64

__device__ __forceinline__ float gelu_exact(float v) {
    return 0.5f * v * (1.0f + erff(v * 0.70710678118654752440f));
}

// ---------------- degree / norm ----------------
__global__ void ecnt_init(int* __restrict__ ecnt, int n) {
    int i = blockIdx.x * 256 + threadIdx.x;
    if (i < n) ecnt[i] = 0;
}

__global__ void ecnt_count(const int* __restrict__ dst, int* __restrict__ ecnt, int e) {
    int i = blockIdx.x * 256 + threadIdx.x;
    if (i < e) atomicAdd(&ecnt[dst[i]], 1);
}

__global__ void dinv_k(const int* __restrict__ ecnt, float* __restrict__ dinv, int n) {
    int i = blockIdx.x * 256 + threadIdx.x;
    if (i < n) dinv[i] = rsqrtf((float)(ecnt[i] + 1));  // +1 self loop
}

// ---------------- exclusive scan (rowptr) ----------------
__global__ void scan_block(const int* __restrict__ ecnt, int* __restrict__ rowptr,
                           int* __restrict__ bsum, int n) {
    __shared__ int tmp[256];
    int i = blockIdx.x * 256 + threadIdx.x;
    int v = (i < n) ? ecnt[i] : 0;
    tmp[threadIdx.x] = v;
    __syncthreads();
#pragma unroll
    for (int o = 1; o < 256; o <<= 1) {
        int t = (threadIdx.x >= o) ? tmp[threadIdx.x - o] : 0;
        __syncthreads();
        tmp[threadIdx.x] += t;
        __syncthreads();
    }
    if (i < n) rowptr[i + 1] = tmp[threadIdx.x];
    if (threadIdx.x == 255) bsum[blockIdx.x] = tmp[255];
}

__global__ void scan_sums(int* __restrict__ bsum, int nb) {
    __shared__ int tmp[512];
    int i = threadIdx.x;
    int v = (i < nb) ? bsum[i] : 0;
    tmp[i] = v;
    __syncthreads();
#pragma unroll
    for (int o = 1; o < 512; o <<= 1) {
        int t = (i >= o) ? tmp[i - o] : 0;
        __syncthreads();
        tmp[i] += t;
        __syncthreads();
    }
    if (i < nb) bsum[i] = tmp[i] - v;  // exclusive
}

__global__ void scan_add(int* __restrict__ rowptr, const int* __restrict__ bsum, int n) {
    int i = blockIdx.x * 256 + threadIdx.x;
    if (i < n) rowptr[i + 1] += bsum[blockIdx.x];
    if (i == 0) rowptr[0] = 0;
}

__global__ void cursor_init(const int* __restrict__ rowptr, int* __restrict__ cursor, int n) {
    int i = blockIdx.x * 256 + threadIdx.x;
    if (i < n) cursor[i] = rowptr[i];
}

__global__ void scatter_edges(const int* __restrict__ src, const int* __restrict__ dst,
                              int* __restrict__ cursor, int* __restrict__ eadj, int e) {
    int i = blockIdx.x * 256 + threadIdx.x;
    if (i < e) {
        int pos = atomicAdd(&cursor[dst[i]], 1);
        eadj[pos] = src[i];
    }
}

// ---------------- propagation: CSR gather, one wave per node ----------------
__global__ __launch_bounds__(256) void sgc_gather(const float* __restrict__ hin,
                                                  float* __restrict__ hout,
                                                  const int* __restrict__ rowptr,
                                                  const int* __restrict__ eadj,
                                                  const float* __restrict__ dinv, int n) {
    int row = blockIdx.x * 4 + (threadIdx.x >> 6);
    int lane = threadIdx.x & 63;
    if (row >= n) return;
    float di = dinv[row];
    float2 acc = ((const float2*)(hin + (size_t)row * HID))[lane];
    acc.x *= di * di;
    acc.y *= di * di;
    int j = rowptr[row], end = rowptr[row + 1];
    for (; j + 1 < end; j += 2) {
        int s0 = eadj[j], s1 = eadj[j + 1];
        float w0 = di * dinv[s0], w1 = di * dinv[s1];
        float2 v0 = ((const float2*)(hin + (size_t)s0 * HID))[lane];
        float2 v1 = ((const float2*)(hin + (size_t)s1 * HID))[lane];
        acc.x += v0.x * w0 + v1.x * w1;
        acc.y += v0.y * w0 + v1.y * w1;
    }
    if (j < end) {
        int s = eadj[j];
        float w = di * dinv[s];
        float2 v = ((const float2*)(hin + (size_t)s * HID))[lane];
        acc.x += v.x * w;
        acc.y += v.y * w;
    }
    ((float2*)(hout + (size_t)row * HID))[lane] = acc;
}

// ---------------- generic tiled fp32 GEMM + bias (+gelu) ----------------
template <int BN, int TM, int TN, bool GELU>
__global__ __launch_bounds__(256) void gemm_bias_act(
    const float* __restrict__ A, const float* __restrict__ B,
    const float* __restrict__ bias, float* __restrict__ C, int M, int K) {
    const int BM = 64, BK = 16;
    __shared__ float As[BM][BK];
    __shared__ float Bs[BK][BN];
    const int tid = threadIdx.x;
    const int tx = tid % (BN / TN);
    const int ty = tid / (BN / TN);
    const int row0 = blockIdx.x * BM;

    float acc[TM][TN];
#pragma unroll
    for (int i = 0; i < TM; i++)
#pragma unroll
        for (int j = 0; j < TN; j++) acc[i][j] = 0.0f;

    const int aRow = tid >> 2;
    const int aQuad = tid & 3;
    const int bQuads = BK * BN / 4;

    for (int k0 = 0; k0 < K; k0 += BK) {
        float4 av = make_float4(0.f, 0.f, 0.f, 0.f);
        int gr = row0 + aRow;
        if (gr < M) av = *(const float4*)(A + (size_t)gr * K + k0 + aQuad * 4);
        *(float4*)(&As[aRow][aQuad * 4]) = av;
        const float4* bsrc = (const float4*)(B + (size_t)k0 * BN);
        float4* bdst = (float4*)(&Bs[0][0]);
#pragma unroll
        for (int i = tid; i < bQuads; i += 256) bdst[i] = bsrc[i];
        __syncthreads();
#pragma unroll
        for (int kk = 0; kk < BK; kk++) {
            float a[TM], b[TN];
#pragma unroll
            for (int i = 0; i < TM; i++) a[i] = As[ty * TM + i][kk];
#pragma unroll
            for (int j = 0; j < TN; j++) b[j] = Bs[kk][tx * TN + j];
#pragma unroll
            for (int i = 0; i < TM; i++)
#pragma unroll
                for (int j = 0; j < TN; j++) acc[i][j] += a[i] * b[j];
        }
        __syncthreads();
    }

#pragma unroll
    for (int i = 0; i < TM; i++) {
        int gr = row0 + ty * TM + i;
        if (gr >= M) continue;
        float4 v;
        float* vp = (float*)&v;
#pragma unroll
        for (int j = 0; j < TN; j++) {
            float c = acc[i][j] + bias[tx * TN + j];
            if (GELU) c = gelu_exact(c);
            vp[j] = c;
        }
        *(float4*)(C + (size_t)gr * BN + tx * TN) = v;
    }
}

// ---------------- rowwise LayerNorm over 128 ch (1 wave / row) ----------------
__global__ __launch_bounds__(256) void ln_k(float* __restrict__ h,
                                            const float* __restrict__ g,
                                            const float* __restrict__ be, int n) {
    int row = blockIdx.x * 4 + (threadIdx.x >> 6);
    int lane = threadIdx.x & 63;
    if (row >= n) return;
    float2 v = ((float2*)(h + (size_t)row * HID))[lane];
    float s = v.x + v.y;
    float sq = v.x * v.x + v.y * v.y;
#pragma unroll
    for (int o = 32; o > 0; o >>= 1) {
        s += __shfl_down(s, o);
        sq += __shfl_down(sq, o);
    }
    s = __shfl(s, 0);
    sq = __shfl(sq, 0);
    float mu = s * (1.0f / HID);
    float var = sq * (1.0f / HID) - mu * mu;
    float rs = rsqrtf(var + 1e-5f);
    float2 gv = ((const float2*)g)[lane];
    float2 bv = ((const float2*)be)[lane];
    v.x = (v.x - mu) * rs * gv.x + bv.x;
    v.y = (v.y - mu) * rs * gv.y + bv.y;
    ((float2*)(h + (size_t)row * HID))[lane] = v;
}

extern "C" void kernel_launch(void* const* d_in, const int* in_sizes, int n_in,
                              void* d_out, int out_size, void* d_ws, size_t ws_size,
                              hipStream_t stream) {
    const float* x   = (const float*)d_in[0];
    const int*   ei  = (const int*)d_in[1];
    const float* W1  = (const float*)d_in[2];
    const float* b1  = (const float*)d_in[3];
    const float* g1  = (const float*)d_in[4];
    const float* be1 = (const float*)d_in[5];
    const float* Wc  = (const float*)d_in[6];
    const float* bc  = (const float*)d_in[7];
    const float* g2  = (const float*)d_in[8];
    const float* be2 = (const float*)d_in[9];
    const float* W2  = (const float*)d_in[10];
    const float* b2  = (const float*)d_in[11];
    float* out = (float*)d_out;

    const int N = in_sizes[0] / IN_CH;  // 100000
    const int E = in_sizes[1] / 2;      // 1600000
    const int* src = ei;
    const int* dst = ei + E;

    // workspace layout
    char* ws = (char*)d_ws;
    size_t off = 0;
    auto alloc = [&](size_t bytes) {
        void* p = ws + off;
        off = (off + bytes + 255) & ~(size_t)255;
        return p;
    };
    int*   ecnt   = (int*)alloc((size_t)N * 4);
    float* dinv   = (float*)alloc((size_t)N * 4);
    int*   rowptr = (int*)alloc((size_t)(N + 1) * 4);
    int*   cursor = (int*)alloc((size_t)N * 4);
    int*   bsum   = (int*)alloc((size_t)4096 * 4);
    int*   eadj   = (int*)alloc((size_t)E * 4);
    float* bufA   = (float*)alloc((size_t)N * HID * 4);
    float* bufB   = (float*)alloc((size_t)N * HID * 4);

    const int B = 256;
    const int nBlkN = (N + B - 1) / B;  // 391
    const int nBlkE = (E + B - 1) / B;

    // degrees + norm + CSR build
    ecnt_init<<<nBlkN, B, 0, stream>>>(ecnt, N);
    ecnt_count<<<nBlkE, B, 0, stream>>>(dst, ecnt, E);
    dinv_k<<<nBlkN, B, 0, stream>>>(ecnt, dinv, N);
    scan_block<<<nBlkN, B, 0, stream>>>(ecnt, rowptr, bsum, N);
    scan_sums<<<1, 512, 0, stream>>>(bsum, nBlkN);
    scan_add<<<nBlkN, B, 0, stream>>>(rowptr, bsum, N);
    cursor_init<<<nBlkN, B, 0, stream>>>(rowptr, cursor, N);
    scatter_edges<<<nBlkE, B, 0, stream>>>(src, dst, cursor, eadj, E);

    // lin1 + gelu -> bufA ; LN in place
    int gblk = (N + 63) / 64;
    gemm_bias_act<HID, 8, 4, true><<<gblk, B, 0, stream>>>(x, W1, b1, bufA, N, IN_CH);
    ln_k<<<(N + 3) / 4, B, 0, stream>>>(bufA, g1, be1, N);

    // hops: bufA -> bufB -> bufA
    sgc_gather<<<(N + 3) / 4, B, 0, stream>>>(bufA, bufB, rowptr, eadj, dinv, N);
    sgc_gather<<<(N + 3) / 4, B, 0, stream>>>(bufB, bufA, rowptr, eadj, dinv, N);

    // Wc + gelu -> bufB ; LN in place
    gemm_bias_act<HID, 8, 4, true><<<gblk, B, 0, stream>>>(bufA, Wc, bc, bufB, N, HID);
    ln_k<<<(N + 3) / 4, B, 0, stream>>>(bufB, g2, be2, N);

    // W2 -> out
    gemm_bias_act<OUT_CH, 4, 4, false><<<gblk, B, 0, stream>>>(bufB, W2, b2, out, N, HID);
}

// Round 3
// 808.176 us; speedup vs baseline: 7.4609x; 1.2809x over previous
//
#include <hip/hip_runtime.h>
#include <math.h>

#define N_NODES 100000
#define N_EDGES 1600000
#define IN_CH 512
#define HID 128
#define OUT_CH 64

typedef __attribute__((ext_vector_type(8))) short bf16x8;
typedef __attribute__((ext_vector_type(4))) float f32x4;

__device__ __forceinline__ float gelu_exact(float v) {
    return 0.5f * v * (1.0f + erff(v * 0.70710678118654752440f));
}

__device__ __forceinline__ unsigned short bf16r(float f) {
    union { float f; unsigned int u; } v;
    v.f = f;
    unsigned int r = v.u + 0x7fffu + ((v.u >> 16) & 1u);
    return (unsigned short)(r >> 16);
}

__device__ __forceinline__ float bf16f(unsigned short h) {
    union { unsigned int u; float f; } v;
    v.u = ((unsigned int)h) << 16;
    return v.f;
}

// ---------------- CSR build ----------------
__global__ void ecnt_init(int* __restrict__ ecnt, int n) {
    int i = blockIdx.x * 256 + threadIdx.x;
    if (i < n) ecnt[i] = 0;
}

__global__ void ecnt_count(const int* __restrict__ dst, int* __restrict__ ecnt, int e) {
    int i = blockIdx.x * 256 + threadIdx.x;
    if (i < e) atomicAdd(&ecnt[dst[i]], 1);
}

__global__ void dinv_k(const int* __restrict__ ecnt, float* __restrict__ dinv, int n) {
    int i = blockIdx.x * 256 + threadIdx.x;
    if (i < n) dinv[i] = rsqrtf((float)(ecnt[i] + 1));  // +1 self loop
}

__global__ void scan_block(const int* __restrict__ ecnt, int* __restrict__ rowptr,
                           int* __restrict__ bsum, int n) {
    __shared__ int tmp[256];
    int i = blockIdx.x * 256 + threadIdx.x;
    int v = (i < n) ? ecnt[i] : 0;
    tmp[threadIdx.x] = v;
    __syncthreads();
#pragma unroll
    for (int o = 1; o < 256; o <<= 1) {
        int t = (threadIdx.x >= o) ? tmp[threadIdx.x - o] : 0;
        __syncthreads();
        tmp[threadIdx.x] += t;
        __syncthreads();
    }
    if (i < n) rowptr[i + 1] = tmp[threadIdx.x];
    if (threadIdx.x == 255) bsum[blockIdx.x] = tmp[255];
}

__global__ void scan_sums(int* __restrict__ bsum, int nb) {
    __shared__ int tmp[512];
    int i = threadIdx.x;
    int v = (i < nb) ? bsum[i] : 0;
    tmp[i] = v;
    __syncthreads();
#pragma unroll
    for (int o = 1; o < 512; o <<= 1) {
        int t = (i >= o) ? tmp[i - o] : 0;
        __syncthreads();
        tmp[i] += t;
        __syncthreads();
    }
    if (i < nb) bsum[i] = tmp[i] - v;  // exclusive
}

__global__ void scan_add(int* __restrict__ rowptr, const int* __restrict__ bsum, int n) {
    int i = blockIdx.x * 256 + threadIdx.x;
    if (i < n) rowptr[i + 1] += bsum[blockIdx.x];
    if (i == 0) rowptr[0] = 0;
}

__global__ void cursor_init(const int* __restrict__ rowptr, int* __restrict__ cursor, int n) {
    int i = blockIdx.x * 256 + threadIdx.x;
    if (i < n) cursor[i] = rowptr[i];
}

__global__ void scatter_edges(const int* __restrict__ src, const int* __restrict__ dst,
                              int* __restrict__ cursor, int* __restrict__ eadj, int e) {
    int i = blockIdx.x * 256 + threadIdx.x;
    if (i < e) {
        int pos = atomicAdd(&cursor[dst[i]], 1);
        eadj[pos] = src[i];
    }
}

// ---------------- weight transpose+convert: out[n][k] = bf16(in[k][n]) ----------------
__global__ void conv_t(const float* __restrict__ in, unsigned short* __restrict__ out,
                       int Kdim, int Nc) {
    int idx = blockIdx.x * 256 + threadIdx.x;
    if (idx >= Kdim * Nc) return;
    int n = idx / Kdim, k = idx % Kdim;
    out[idx] = bf16r(in[(size_t)k * Nc + n]);
}

// ---------------- MFMA GEMM: C[M,N] = act(A[M,K] @ BT[N,K]^T + bias) ----------------
// A32: A is fp32 (converted during staging) else bf16. LN: fused GELU+LayerNorm, bf16 out;
// else bias only, fp32 out. Block: 256 thr = 4 waves, tile 128 x N, BK=32.
template <int K, int NT, bool A32, bool LN>
__global__ __launch_bounds__(256) void gemm_mfma(
    const void* __restrict__ Aptr, const unsigned short* __restrict__ BT,
    const float* __restrict__ bias, const float* __restrict__ gamma,
    const float* __restrict__ beta, void* __restrict__ Cptr, int M) {
    constexpr int BM = 128, BKP = 40, N = NT * 16;
    __shared__ unsigned short As[BM * BKP];
    __shared__ unsigned short Bs[N * BKP];
    const int tid = threadIdx.x;
    const int wave = tid >> 6, lane = tid & 63;
    const int l15 = lane & 15, quad = lane >> 4;
    const int row0 = blockIdx.x * BM;

    f32x4 acc[2][NT];
#pragma unroll
    for (int mi = 0; mi < 2; mi++)
#pragma unroll
        for (int ni = 0; ni < NT; ni++) acc[mi][ni] = (f32x4){0.f, 0.f, 0.f, 0.f};

    float bia[NT], gam[NT], bet[NT];
#pragma unroll
    for (int ni = 0; ni < NT; ni++) {
        bia[ni] = bias[ni * 16 + l15];
        if (LN) {
            gam[ni] = gamma[ni * 16 + l15];
            bet[ni] = beta[ni * 16 + l15];
        }
    }

    for (int k0 = 0; k0 < K; k0 += 32) {
        // stage A (128 rows x 32 cols)
        if (A32) {
            const float* A = (const float*)Aptr;
#pragma unroll
            for (int i = 0; i < 4; i++) {
                int idx = tid + 256 * i;
                int r = idx >> 3, c4 = idx & 7;
                float4 v = make_float4(0.f, 0.f, 0.f, 0.f);
                int gr = row0 + r;
                if (gr < M) v = *(const float4*)(A + (size_t)gr * K + k0 + c4 * 4);
                uint2 w;
                w.x = (unsigned int)bf16r(v.x) | ((unsigned int)bf16r(v.y) << 16);
                w.y = (unsigned int)bf16r(v.z) | ((unsigned int)bf16r(v.w) << 16);
                *(uint2*)(&As[r * BKP + c4 * 4]) = w;
            }
        } else {
            const unsigned short* A = (const unsigned short*)Aptr;
#pragma unroll
            for (int i = 0; i < 2; i++) {
                int idx = tid + 256 * i;
                int r = idx >> 2, c8 = idx & 3;
                int4 d = make_int4(0, 0, 0, 0);
                int gr = row0 + r;
                if (gr < M) d = *(const int4*)(A + (size_t)gr * K + k0 + c8 * 8);
                *(int4*)(&As[r * BKP + c8 * 8]) = d;
            }
        }
        // stage B (N rows x 32 cols of BT)
#pragma unroll
        for (int i = 0; i < (N * 4) / 256; i++) {
            int idx = tid + 256 * i;
            int r = idx >> 2, c8 = idx & 3;
            int4 d = *(const int4*)(BT + (size_t)r * K + k0 + c8 * 8);
            *(int4*)(&Bs[r * BKP + c8 * 8]) = d;
        }
        __syncthreads();

        bf16x8 a[2], b[NT];
#pragma unroll
        for (int mi = 0; mi < 2; mi++)
            a[mi] = *(const bf16x8*)(&As[(wave * 32 + mi * 16 + l15) * BKP + quad * 8]);
#pragma unroll
        for (int ni = 0; ni < NT; ni++)
            b[ni] = *(const bf16x8*)(&Bs[(ni * 16 + l15) * BKP + quad * 8]);
#pragma unroll
        for (int mi = 0; mi < 2; mi++)
#pragma unroll
            for (int ni = 0; ni < NT; ni++)
                acc[mi][ni] =
                    __builtin_amdgcn_mfma_f32_16x16x32_bf16(a[mi], b[ni], acc[mi][ni], 0, 0, 0);
        __syncthreads();
    }

    // epilogue: D row = quad*4+reg (+16*mi +32*wave), col = ni*16+l15
#pragma unroll
    for (int mi = 0; mi < 2; mi++) {
#pragma unroll
        for (int r = 0; r < 4; r++) {
            int grow = row0 + wave * 32 + mi * 16 + quad * 4 + r;
            if (LN) {
                float g[NT];
                float s = 0.f, sq = 0.f;
#pragma unroll
                for (int ni = 0; ni < NT; ni++) {
                    float v = gelu_exact(acc[mi][ni][r] + bia[ni]);
                    g[ni] = v;
                    s += v;
                    sq += v * v;
                }
#pragma unroll
                for (int m = 1; m < 16; m <<= 1) {
                    s += __shfl_xor(s, m);
                    sq += __shfl_xor(sq, m);
                }
                float mu = s * (1.0f / N);
                float var = sq * (1.0f / N) - mu * mu;
                float rs = rsqrtf(var + 1e-5f);
                if (grow < M) {
                    unsigned short* C = (unsigned short*)Cptr;
#pragma unroll
                    for (int ni = 0; ni < NT; ni++) {
                        float o = (g[ni] - mu) * rs * gam[ni] + bet[ni];
                        C[(size_t)grow * N + ni * 16 + l15] = bf16r(o);
                    }
                }
            } else {
                if (grow < M) {
                    float* C = (float*)Cptr;
#pragma unroll
                    for (int ni = 0; ni < NT; ni++)
                        C[(size_t)grow * N + ni * 16 + l15] = acc[mi][ni][r] + bia[ni];
                }
            }
        }
    }
}

// ---------------- propagation: CSR gather on bf16 rows, one wave per node ----------------
__global__ __launch_bounds__(256) void sgc_gather_bf16(const unsigned short* __restrict__ hin,
                                                       unsigned short* __restrict__ hout,
                                                       const int* __restrict__ rowptr,
                                                       const int* __restrict__ eadj,
                                                       const float* __restrict__ dinv, int n) {
    int row = blockIdx.x * 4 + (threadIdx.x >> 6);
    int lane = threadIdx.x & 63;
    if (row >= n) return;
    float di = dinv[row];
    unsigned int u = *(const unsigned int*)(hin + (size_t)row * HID + lane * 2);
    float ax = bf16f((unsigned short)(u & 0xffff)) * di * di;
    float ay = bf16f((unsigned short)(u >> 16)) * di * di;
    int j = rowptr[row], end = rowptr[row + 1];
    for (; j + 1 < end; j += 2) {
        int s0 = eadj[j], s1 = eadj[j + 1];
        float w0 = di * dinv[s0], w1 = di * dinv[s1];
        unsigned int u0 = *(const unsigned int*)(hin + (size_t)s0 * HID + lane * 2);
        unsigned int u1 = *(const unsigned int*)(hin + (size_t)s1 * HID + lane * 2);
        ax += bf16f((unsigned short)(u0 & 0xffff)) * w0 + bf16f((unsigned short)(u1 & 0xffff)) * w1;
        ay += bf16f((unsigned short)(u0 >> 16)) * w0 + bf16f((unsigned short)(u1 >> 16)) * w1;
    }
    if (j < end) {
        int s = eadj[j];
        float w = di * dinv[s];
        unsigned int u0 = *(const unsigned int*)(hin + (size_t)s * HID + lane * 2);
        ax += bf16f((unsigned short)(u0 & 0xffff)) * w;
        ay += bf16f((unsigned short)(u0 >> 16)) * w;
    }
    unsigned int o = (unsigned int)bf16r(ax) | ((unsigned int)bf16r(ay) << 16);
    *(unsigned int*)(hout + (size_t)row * HID + lane * 2) = o;
}

extern "C" void kernel_launch(void* const* d_in, const int* in_sizes, int n_in,
                              void* d_out, int out_size, void* d_ws, size_t ws_size,
                              hipStream_t stream) {
    const float* x   = (const float*)d_in[0];
    const int*   ei  = (const int*)d_in[1];
    const float* W1  = (const float*)d_in[2];
    const float* b1  = (const float*)d_in[3];
    const float* g1  = (const float*)d_in[4];
    const float* be1 = (const float*)d_in[5];
    const float* Wc  = (const float*)d_in[6];
    const float* bc  = (const float*)d_in[7];
    const float* g2  = (const float*)d_in[8];
    const float* be2 = (const float*)d_in[9];
    const float* W2  = (const float*)d_in[10];
    const float* b2  = (const float*)d_in[11];
    float* out = (float*)d_out;

    const int N = in_sizes[0] / IN_CH;  // 100000
    const int E = in_sizes[1] / 2;      // 1600000
    const int* src = ei;
    const int* dst = ei + E;

    char* ws = (char*)d_ws;
    size_t off = 0;
    auto alloc = [&](size_t bytes) {
        void* p = ws + off;
        off = (off + bytes + 255) & ~(size_t)255;
        return p;
    };
    int*   ecnt   = (int*)alloc((size_t)N * 4);
    float* dinv   = (float*)alloc((size_t)N * 4);
    int*   rowptr = (int*)alloc((size_t)(N + 1) * 4);
    int*   cursor = (int*)alloc((size_t)N * 4);
    int*   bsum   = (int*)alloc((size_t)4096 * 4);
    int*   eadj   = (int*)alloc((size_t)E * 4);
    unsigned short* W1T = (unsigned short*)alloc((size_t)HID * IN_CH * 2);
    unsigned short* WcT = (unsigned short*)alloc((size_t)HID * HID * 2);
    unsigned short* W2T = (unsigned short*)alloc((size_t)OUT_CH * HID * 2);
    unsigned short* hA  = (unsigned short*)alloc((size_t)N * HID * 2);
    unsigned short* hB  = (unsigned short*)alloc((size_t)N * HID * 2);

    const int B = 256;
    const int nBlkN = (N + B - 1) / B;
    const int nBlkE = (E + B - 1) / B;

    // CSR build + norm
    ecnt_init<<<nBlkN, B, 0, stream>>>(ecnt, N);
    ecnt_count<<<nBlkE, B, 0, stream>>>(dst, ecnt, E);
    dinv_k<<<nBlkN, B, 0, stream>>>(ecnt, dinv, N);
    scan_block<<<nBlkN, B, 0, stream>>>(ecnt, rowptr, bsum, N);
    scan_sums<<<1, 512, 0, stream>>>(bsum, nBlkN);
    scan_add<<<nBlkN, B, 0, stream>>>(rowptr, bsum, N);
    cursor_init<<<nBlkN, B, 0, stream>>>(rowptr, cursor, N);
    scatter_edges<<<nBlkE, B, 0, stream>>>(src, dst, cursor, eadj, E);

    // weight prep
    conv_t<<<(IN_CH * HID + 255) / 256, B, 0, stream>>>(W1, W1T, IN_CH, HID);
    conv_t<<<(HID * HID + 255) / 256, B, 0, stream>>>(Wc, WcT, HID, HID);
    conv_t<<<(HID * OUT_CH + 255) / 256, B, 0, stream>>>(W2, W2T, HID, OUT_CH);

    const int gblk = (N + 127) / 128;
    // lin1 + gelu + LN -> hA (bf16)
    gemm_mfma<IN_CH, 8, true, true><<<gblk, B, 0, stream>>>(x, W1T, b1, g1, be1, hA, N);
    // hops: hA -> hB -> hA
    sgc_gather_bf16<<<(N + 3) / 4, B, 0, stream>>>(hA, hB, rowptr, eadj, dinv, N);
    sgc_gather_bf16<<<(N + 3) / 4, B, 0, stream>>>(hB, hA, rowptr, eadj, dinv, N);
    // Wc + gelu + LN -> hB (bf16)
    gemm_mfma<HID, 8, false, true><<<gblk, B, 0, stream>>>(hA, WcT, bc, g2, be2, hB, N);
    // W2 + bias -> out (fp32)
    gemm_mfma<HID, 4, false, false><<<gblk, B, 0, stream>>>(hB, W2T, b2, nullptr, nullptr, out, N);
}

// Round 4
// 693.255 us; speedup vs baseline: 8.6978x; 1.1658x over previous
//
#include <hip/hip_runtime.h>
#include <math.h>

#define N_NODES 100000
#define N_EDGES 1600000
#define IN_CH 512
#define HID 128
#define OUT_CH 64

typedef __attribute__((ext_vector_type(8))) short bf16x8;
typedef __attribute__((ext_vector_type(4))) float f32x4;

__device__ __forceinline__ float gelu_exact(float v) {
    return 0.5f * v * (1.0f + erff(v * 0.70710678118654752440f));
}

__device__ __forceinline__ unsigned short bf16r(float f) {
    union { float f; unsigned int u; } v;
    v.f = f;
    unsigned int r = v.u + 0x7fffu + ((v.u >> 16) & 1u);
    return (unsigned short)(r >> 16);
}

__device__ __forceinline__ float bf16f(unsigned short h) {
    union { unsigned int u; float f; } v;
    v.u = ((unsigned int)h) << 16;
    return v.f;
}

// ---------------- CSR build ----------------
__global__ void ecnt_init(int* __restrict__ ecnt, int n) {
    int i = blockIdx.x * 256 + threadIdx.x;
    if (i < n) ecnt[i] = 0;
}

__global__ void ecnt_count(const int* __restrict__ dst, int* __restrict__ ecnt, int e) {
    int i = blockIdx.x * 256 + threadIdx.x;
    if (i < e) atomicAdd(&ecnt[dst[i]], 1);
}

__global__ void dinv_k(const int* __restrict__ ecnt, float* __restrict__ dinv, int n) {
    int i = blockIdx.x * 256 + threadIdx.x;
    if (i < n) dinv[i] = rsqrtf((float)(ecnt[i] + 1));  // +1 self loop
}

__global__ void scan_block(const int* __restrict__ ecnt, int* __restrict__ rowptr,
                           int* __restrict__ bsum, int n) {
    __shared__ int tmp[256];
    int i = blockIdx.x * 256 + threadIdx.x;
    int v = (i < n) ? ecnt[i] : 0;
    tmp[threadIdx.x] = v;
    __syncthreads();
#pragma unroll
    for (int o = 1; o < 256; o <<= 1) {
        int t = (threadIdx.x >= o) ? tmp[threadIdx.x - o] : 0;
        __syncthreads();
        tmp[threadIdx.x] += t;
        __syncthreads();
    }
    if (i < n) rowptr[i + 1] = tmp[threadIdx.x];
    if (threadIdx.x == 255) bsum[blockIdx.x] = tmp[255];
}

__global__ void scan_sums(int* __restrict__ bsum, int nb) {
    __shared__ int tmp[512];
    int i = threadIdx.x;
    int v = (i < nb) ? bsum[i] : 0;
    tmp[i] = v;
    __syncthreads();
#pragma unroll
    for (int o = 1; o < 512; o <<= 1) {
        int t = (i >= o) ? tmp[i - o] : 0;
        __syncthreads();
        tmp[i] += t;
        __syncthreads();
    }
    if (i < nb) bsum[i] = tmp[i] - v;  // exclusive
}

__global__ void scan_add(int* __restrict__ rowptr, const int* __restrict__ bsum, int n) {
    int i = blockIdx.x * 256 + threadIdx.x;
    if (i < n) rowptr[i + 1] += bsum[blockIdx.x];
    if (i == 0) rowptr[0] = 0;
}

__global__ void cursor_init(const int* __restrict__ rowptr, int* __restrict__ cursor, int n) {
    int i = blockIdx.x * 256 + threadIdx.x;
    if (i < n) cursor[i] = rowptr[i];
}

__global__ void scatter_edges(const int* __restrict__ src, const int* __restrict__ dst,
                              int* __restrict__ cursor, int* __restrict__ eadj, int e) {
    int i = blockIdx.x * 256 + threadIdx.x;
    if (i < e) {
        int pos = atomicAdd(&cursor[dst[i]], 1);
        eadj[pos] = src[i];
    }
}

// ---------------- weight transpose+convert: out[n][k] = bf16(in[k][n]) ----------------
__global__ void conv_t(const float* __restrict__ in, unsigned short* __restrict__ out,
                       int Kdim, int Nc) {
    int idx = blockIdx.x * 256 + threadIdx.x;
    if (idx >= Kdim * Nc) return;
    int n = idx / Kdim, k = idx % Kdim;
    out[idx] = bf16r(in[(size_t)k * Nc + n]);
}

// ---------------- MFMA GEMM: C = act(A[M,K] @ BT[N,K]^T + bias) ----------------
// BM=64 tile, BK=32, double-buffered LDS + register prefetch, XOR-swizzled LDS.
// A32: A fp32 (converted in staging regs) else bf16. LN: fused GELU+LN, bf16 out;
// else bias only, fp32 out.
template <int K, int NT, bool A32, bool LN>
__global__ __launch_bounds__(256) void gemm_mfma(
    const void* __restrict__ Aptr, const unsigned short* __restrict__ BT,
    const float* __restrict__ bias, const float* __restrict__ gamma,
    const float* __restrict__ beta, void* __restrict__ Cptr, int M) {
    constexpr int BM = 64, N = NT * 16, NSTEP = K / 32;
    __shared__ unsigned short As[2][BM * 32];
    __shared__ unsigned short Bs[2][N * 32];
    const int tid = threadIdx.x;
    const int wave = tid >> 6, lane = tid & 63;
    const int l15 = lane & 15, quad = lane >> 4;
    const int row0 = blockIdx.x * BM;

    // staging mapping: thread -> (row sr, k-granule sc of 8 bf16)
    const int sr = tid >> 2, sc = tid & 3;
    const int sswz = sc ^ ((sr >> 2) & 3);  // ((sr+64)>>2)&3 == (sr>>2)&3, reuse for B row sr+64
    const bool aok = (row0 + sr) < M;

    const float* A32p = (const float*)Aptr + (size_t)(row0 + sr) * K + sc * 8;
    const unsigned short* A16p = (const unsigned short*)Aptr + (size_t)(row0 + sr) * K + sc * 8;
    const unsigned short* B0p = BT + (size_t)sr * K + sc * 8;
    const unsigned short* B1p = BT + (size_t)(sr + 64) * K + sc * 8;

    // prefetch registers (step 0)
    float4 pa0, pa1;
    int4 pa16, pb0, pb1;
    if (A32) {
        pa0 = aok ? *(const float4*)(A32p) : make_float4(0.f, 0.f, 0.f, 0.f);
        pa1 = aok ? *(const float4*)(A32p + 4) : make_float4(0.f, 0.f, 0.f, 0.f);
    } else {
        pa16 = aok ? *(const int4*)(A16p) : make_int4(0, 0, 0, 0);
    }
    pb0 = *(const int4*)(B0p);
    if (NT == 8) pb1 = *(const int4*)(B1p);

    f32x4 acc[NT];
#pragma unroll
    for (int ni = 0; ni < NT; ni++) acc[ni] = (f32x4){0.f, 0.f, 0.f, 0.f};

    float bia[NT], gam[NT], bet[NT];
#pragma unroll
    for (int ni = 0; ni < NT; ni++) {
        bia[ni] = bias[ni * 16 + l15];
        if (LN) {
            gam[ni] = gamma[ni * 16 + l15];
            bet[ni] = beta[ni * 16 + l15];
        }
    }

    const int fswz = quad ^ ((l15 >> 2) & 3);
    const int aoff = (wave * 16 + l15) * 32 + fswz * 8;

    for (int step = 0; step < NSTEP; step++) {
        const int buf = step & 1;
        // store prefetched tile -> LDS[buf]
        if (A32) {
            int4 w;
            w.x = (int)((unsigned int)bf16r(pa0.x) | ((unsigned int)bf16r(pa0.y) << 16));
            w.y = (int)((unsigned int)bf16r(pa0.z) | ((unsigned int)bf16r(pa0.w) << 16));
            w.z = (int)((unsigned int)bf16r(pa1.x) | ((unsigned int)bf16r(pa1.y) << 16));
            w.w = (int)((unsigned int)bf16r(pa1.z) | ((unsigned int)bf16r(pa1.w) << 16));
            *(int4*)&As[buf][sr * 32 + sswz * 8] = w;
        } else {
            *(int4*)&As[buf][sr * 32 + sswz * 8] = pa16;
        }
        *(int4*)&Bs[buf][sr * 32 + sswz * 8] = pb0;
        if (NT == 8) *(int4*)&Bs[buf][(sr + 64) * 32 + sswz * 8] = pb1;
        __syncthreads();
        // issue next step's global loads (in flight during MFMA below)
        if (step + 1 < NSTEP) {
            const int ko = (step + 1) * 32;
            if (A32) {
                pa0 = aok ? *(const float4*)(A32p + ko) : make_float4(0.f, 0.f, 0.f, 0.f);
                pa1 = aok ? *(const float4*)(A32p + ko + 4) : make_float4(0.f, 0.f, 0.f, 0.f);
            } else {
                pa16 = aok ? *(const int4*)(A16p + ko) : make_int4(0, 0, 0, 0);
            }
            pb0 = *(const int4*)(B0p + ko);
            if (NT == 8) pb1 = *(const int4*)(B1p + ko);
        }
        // compute
        bf16x8 a = *(const bf16x8*)&As[buf][aoff];
#pragma unroll
        for (int ni = 0; ni < NT; ni++) {
            bf16x8 b = *(const bf16x8*)&Bs[buf][(ni * 16 + l15) * 32 + fswz * 8];
            acc[ni] = __builtin_amdgcn_mfma_f32_16x16x32_bf16(a, b, acc[ni], 0, 0, 0);
        }
    }

    // epilogue: D row = wave*16 + quad*4 + r, col = ni*16 + l15
#pragma unroll
    for (int r = 0; r < 4; r++) {
        int grow = row0 + wave * 16 + quad * 4 + r;
        if (LN) {
            float g[NT];
            float s = 0.f, sq = 0.f;
#pragma unroll
            for (int ni = 0; ni < NT; ni++) {
                float v = gelu_exact(acc[ni][r] + bia[ni]);
                g[ni] = v;
                s += v;
                sq += v * v;
            }
#pragma unroll
            for (int m = 1; m < 16; m <<= 1) {
                s += __shfl_xor(s, m);
                sq += __shfl_xor(sq, m);
            }
            float mu = s * (1.0f / N);
            float var = sq * (1.0f / N) - mu * mu;
            float rs = rsqrtf(var + 1e-5f);
            if (grow < M) {
                unsigned short* C = (unsigned short*)Cptr;
#pragma unroll
                for (int ni = 0; ni < NT; ni++) {
                    float o = (g[ni] - mu) * rs * gam[ni] + bet[ni];
                    C[(size_t)grow * N + ni * 16 + l15] = bf16r(o);
                }
            }
        } else {
            if (grow < M) {
                float* C = (float*)Cptr;
#pragma unroll
                for (int ni = 0; ni < NT; ni++)
                    C[(size_t)grow * N + ni * 16 + l15] = acc[ni][r] + bia[ni];
            }
        }
    }
}

// ---------------- propagation: CSR gather on bf16 rows, one wave per node ----------------
__global__ __launch_bounds__(256) void sgc_gather_bf16(const unsigned short* __restrict__ hin,
                                                       unsigned short* __restrict__ hout,
                                                       const int* __restrict__ rowptr,
                                                       const int* __restrict__ eadj,
                                                       const float* __restrict__ dinv, int n) {
    int row = blockIdx.x * 4 + (threadIdx.x >> 6);
    int lane = threadIdx.x & 63;
    if (row >= n) return;
    float di = dinv[row];
    unsigned int u = *(const unsigned int*)(hin + (size_t)row * HID + lane * 2);
    float ax = bf16f((unsigned short)(u & 0xffff)) * di * di;
    float ay = bf16f((unsigned short)(u >> 16)) * di * di;
    int j = rowptr[row], end = rowptr[row + 1];
    for (; j + 3 < end; j += 4) {
        int s0 = eadj[j], s1 = eadj[j + 1], s2 = eadj[j + 2], s3 = eadj[j + 3];
        float d0 = dinv[s0], d1 = dinv[s1], d2 = dinv[s2], d3 = dinv[s3];
        unsigned int u0 = *(const unsigned int*)(hin + (size_t)s0 * HID + lane * 2);
        unsigned int u1 = *(const unsigned int*)(hin + (size_t)s1 * HID + lane * 2);
        unsigned int u2 = *(const unsigned int*)(hin + (size_t)s2 * HID + lane * 2);
        unsigned int u3 = *(const unsigned int*)(hin + (size_t)s3 * HID + lane * 2);
        float w0 = di * d0, w1 = di * d1, w2 = di * d2, w3 = di * d3;
        ax += bf16f((unsigned short)(u0 & 0xffff)) * w0 + bf16f((unsigned short)(u1 & 0xffff)) * w1 +
              bf16f((unsigned short)(u2 & 0xffff)) * w2 + bf16f((unsigned short)(u3 & 0xffff)) * w3;
        ay += bf16f((unsigned short)(u0 >> 16)) * w0 + bf16f((unsigned short)(u1 >> 16)) * w1 +
              bf16f((unsigned short)(u2 >> 16)) * w2 + bf16f((unsigned short)(u3 >> 16)) * w3;
    }
    for (; j < end; j++) {
        int s = eadj[j];
        float w = di * dinv[s];
        unsigned int u0 = *(const unsigned int*)(hin + (size_t)s * HID + lane * 2);
        ax += bf16f((unsigned short)(u0 & 0xffff)) * w;
        ay += bf16f((unsigned short)(u0 >> 16)) * w;
    }
    unsigned int o = (unsigned int)bf16r(ax) | ((unsigned int)bf16r(ay) << 16);
    *(unsigned int*)(hout + (size_t)row * HID + lane * 2) = o;
}

extern "C" void kernel_launch(void* const* d_in, const int* in_sizes, int n_in,
                              void* d_out, int out_size, void* d_ws, size_t ws_size,
                              hipStream_t stream) {
    const float* x   = (const float*)d_in[0];
    const int*   ei  = (const int*)d_in[1];
    const float* W1  = (const float*)d_in[2];
    const float* b1  = (const float*)d_in[3];
    const float* g1  = (const float*)d_in[4];
    const float* be1 = (const float*)d_in[5];
    const float* Wc  = (const float*)d_in[6];
    const float* bc  = (const float*)d_in[7];
    const float* g2  = (const float*)d_in[8];
    const float* be2 = (const float*)d_in[9];
    const float* W2  = (const float*)d_in[10];
    const float* b2  = (const float*)d_in[11];
    float* out = (float*)d_out;

    const int N = in_sizes[0] / IN_CH;  // 100000
    const int E = in_sizes[1] / 2;      // 1600000
    const int* src = ei;
    const int* dst = ei + E;

    char* ws = (char*)d_ws;
    size_t off = 0;
    auto alloc = [&](size_t bytes) {
        void* p = ws + off;
        off = (off + bytes + 255) & ~(size_t)255;
        return p;
    };
    int*   ecnt   = (int*)alloc((size_t)N * 4);
    float* dinv   = (float*)alloc((size_t)N * 4);
    int*   rowptr = (int*)alloc((size_t)(N + 1) * 4);
    int*   cursor = (int*)alloc((size_t)N * 4);
    int*   bsum   = (int*)alloc((size_t)4096 * 4);
    int*   eadj   = (int*)alloc((size_t)E * 4);
    unsigned short* W1T = (unsigned short*)alloc((size_t)HID * IN_CH * 2);
    unsigned short* WcT = (unsigned short*)alloc((size_t)HID * HID * 2);
    unsigned short* W2T = (unsigned short*)alloc((size_t)OUT_CH * HID * 2);
    unsigned short* hA  = (unsigned short*)alloc((size_t)N * HID * 2);
    unsigned short* hB  = (unsigned short*)alloc((size_t)N * HID * 2);

    const int B = 256;
    const int nBlkN = (N + B - 1) / B;
    const int nBlkE = (E + B - 1) / B;

    // CSR build + norm
    ecnt_init<<<nBlkN, B, 0, stream>>>(ecnt, N);
    ecnt_count<<<nBlkE, B, 0, stream>>>(dst, ecnt, E);
    dinv_k<<<nBlkN, B, 0, stream>>>(ecnt, dinv, N);
    scan_block<<<nBlkN, B, 0, stream>>>(ecnt, rowptr, bsum, N);
    scan_sums<<<1, 512, 0, stream>>>(bsum, nBlkN);
    scan_add<<<nBlkN, B, 0, stream>>>(rowptr, bsum, N);
    cursor_init<<<nBlkN, B, 0, stream>>>(rowptr, cursor, N);
    scatter_edges<<<nBlkE, B, 0, stream>>>(src, dst, cursor, eadj, E);

    // weight prep
    conv_t<<<(IN_CH * HID + 255) / 256, B, 0, stream>>>(W1, W1T, IN_CH, HID);
    conv_t<<<(HID * HID + 255) / 256, B, 0, stream>>>(Wc, WcT, HID, HID);
    conv_t<<<(HID * OUT_CH + 255) / 256, B, 0, stream>>>(W2, W2T, HID, OUT_CH);

    const int gblk = (N + 63) / 64;  // 1563
    // lin1 + gelu + LN -> hA (bf16)
    gemm_mfma<IN_CH, 8, true, true><<<gblk, B, 0, stream>>>(x, W1T, b1, g1, be1, hA, N);
    // hops: hA -> hB -> hA
    sgc_gather_bf16<<<(N + 3) / 4, B, 0, stream>>>(hA, hB, rowptr, eadj, dinv, N);
    sgc_gather_bf16<<<(N + 3) / 4, B, 0, stream>>>(hB, hA, rowptr, eadj, dinv, N);
    // Wc + gelu + LN -> hB (bf16)
    gemm_mfma<HID, 8, false, true><<<gblk, B, 0, stream>>>(hA, WcT, bc, g2, be2, hB, N);
    // W2 + bias -> out (fp32)
    gemm_mfma<HID, 4, false, false><<<gblk, B, 0, stream>>>(hB, W2T, b2, nullptr, nullptr, out, N);
}

// Round 5
// 538.802 us; speedup vs baseline: 11.1910x; 1.2867x over previous
//
#include <hip/hip_runtime.h>
#include <math.h>

#define N_NODES 100000
#define N_EDGES 1600000
#define IN_CH 512
#define HID 128
#define OUT_CH 64
#define NBUCK ((N_NODES + 255) / 256)  // 391
#define LBUF_CAP 8192

typedef __attribute__((ext_vector_type(8))) short bf16x8;
typedef __attribute__((ext_vector_type(4))) float f32x4;

__device__ __forceinline__ float gelu_exact(float v) {
    return 0.5f * v * (1.0f + erff(v * 0.70710678118654752440f));
}

__device__ __forceinline__ unsigned short bf16r(float f) {
    union { float f; unsigned int u; } v;
    v.f = f;
    unsigned int r = v.u + 0x7fffu + ((v.u >> 16) & 1u);
    return (unsigned short)(r >> 16);
}

__device__ __forceinline__ float bf16f(unsigned short h) {
    union { unsigned int u; float f; } v;
    v.u = ((unsigned int)h) << 16;
    return v.f;
}

// ---------------- bucketed CSR build ----------------
__global__ void bzero(int* __restrict__ bcnt) {
    if (threadIdx.x < NBUCK) bcnt[threadIdx.x] = 0;
}

__global__ __launch_bounds__(256) void bhist(const int* __restrict__ dst,
                                             int* __restrict__ bcnt, int e) {
    __shared__ int lcnt[NBUCK];
    for (int i = threadIdx.x; i < NBUCK; i += 256) lcnt[i] = 0;
    __syncthreads();
    int base = blockIdx.x * 256 * 16 + threadIdx.x;
#pragma unroll
    for (int i = 0; i < 16; i++) {
        int id = base + i * 256;
        if (id < e) atomicAdd(&lcnt[dst[id] >> 8], 1);
    }
    __syncthreads();
    for (int i = threadIdx.x; i < NBUCK; i += 256)
        if (lcnt[i]) atomicAdd(&bcnt[i], lcnt[i]);
}

__global__ void bscan(const int* __restrict__ bcnt, int* __restrict__ bbase,
                      int* __restrict__ bcur, int* __restrict__ rowptr, int e) {
    __shared__ int tmp[512];
    int i = threadIdx.x;
    int v = (i < NBUCK) ? bcnt[i] : 0;
    tmp[i] = v;
    __syncthreads();
#pragma unroll
    for (int o = 1; o < 512; o <<= 1) {
        int t = (i >= o) ? tmp[i - o] : 0;
        __syncthreads();
        tmp[i] += t;
        __syncthreads();
    }
    if (i <= NBUCK) {
        int excl = (i == 0) ? 0 : tmp[i - 1];
        bbase[i] = excl;
        if (i < NBUCK) bcur[i] = excl;
    }
    if (i == 0) rowptr[N_NODES] = e;
}

// pass A: bin edges into bucket-segmented ebuf, packed (src<<8)|local_dst
__global__ __launch_bounds__(256) void binA(const int* __restrict__ src,
                                            const int* __restrict__ dst,
                                            int* __restrict__ bcur,
                                            unsigned int* __restrict__ ebuf, int e) {
    __shared__ int lcnt[NBUCK];
    __shared__ int gbase[NBUCK];
    const int tid = threadIdx.x;
    for (int i = tid; i < NBUCK; i += 256) lcnt[i] = 0;
    __syncthreads();
    const int base = blockIdx.x * (256 * 16);
    int sv[16];
    short bk[16], rk[16];
    unsigned char ld[16];
#pragma unroll
    for (int i = 0; i < 16; i++) {
        int idx = base + tid + i * 256;
        bk[i] = -1;
        if (idx < e) {
            int d = dst[idx];
            sv[i] = src[idx];
            ld[i] = (unsigned char)(d & 255);
            int b = d >> 8;
            bk[i] = (short)b;
            rk[i] = (short)atomicAdd(&lcnt[b], 1);
        }
    }
    __syncthreads();
    for (int i = tid; i < NBUCK; i += 256)
        if (lcnt[i]) gbase[i] = atomicAdd(&bcur[i], lcnt[i]);
    __syncthreads();
#pragma unroll
    for (int i = 0; i < 16; i++)
        if (bk[i] >= 0)
            ebuf[gbase[bk[i]] + rk[i]] = ((unsigned int)sv[i] << 8) | ld[i];
}

// pass B: per bucket -> local CSR (rowptr, dinv) + coalesced eadj
__global__ __launch_bounds__(256) void binB(const unsigned int* __restrict__ ebuf,
                                            const int* __restrict__ bbase,
                                            int* __restrict__ rowptr, int* __restrict__ eadj,
                                            float* __restrict__ dinv) {
    __shared__ int cnt[256], lofs[256], lcur[256];
    __shared__ int lbuf[LBUF_CAP];
    const int b = blockIdx.x, tid = threadIdx.x;
    const int n0 = b * 256;
    const int nn = min(256, N_NODES - n0);
    const int e0 = bbase[b], e1 = bbase[b + 1];
    const int ecount = e1 - e0;
    cnt[tid] = 0;
    __syncthreads();
    for (int i = tid; i < ecount; i += 256) atomicAdd(&cnt[ebuf[e0 + i] & 255], 1);
    __syncthreads();
    int v = cnt[tid];
    lofs[tid] = v;
    __syncthreads();
#pragma unroll
    for (int o = 1; o < 256; o <<= 1) {
        int t = (tid >= o) ? lofs[tid - o] : 0;
        __syncthreads();
        lofs[tid] += t;
        __syncthreads();
    }
    int excl = lofs[tid] - v;
    lcur[tid] = excl;
    if (tid < nn) {
        rowptr[n0 + tid] = e0 + excl;
        dinv[n0 + tid] = rsqrtf((float)(v + 1));
    }
    __syncthreads();
    for (int i = tid; i < ecount; i += 256) {
        unsigned int w = ebuf[e0 + i];
        int pos = atomicAdd(&lcur[w & 255], 1);
        int s = (int)(w >> 8);
        if (pos < LBUF_CAP) lbuf[pos] = s;
        else eadj[e0 + pos] = s;  // overflow safety (never expected: avg 4092/bucket)
    }
    __syncthreads();
    int lim = min(ecount, LBUF_CAP);
    for (int i = tid; i < lim; i += 256) eadj[e0 + i] = lbuf[i];
}

// ---------------- weight transpose+convert: out[n][k] = bf16(in[k][n]) ----------------
__global__ void conv_t(const float* __restrict__ in, unsigned short* __restrict__ out,
                       int Kdim, int Nc) {
    int idx = blockIdx.x * 256 + threadIdx.x;
    if (idx >= Kdim * Nc) return;
    int n = idx / Kdim, k = idx % Kdim;
    out[idx] = bf16r(in[(size_t)k * Nc + n]);
}

// ---------------- MFMA GEMM (as R3: BM=64, dbuf LDS, XOR swizzle) ----------------
template <int K, int NT, bool A32, bool LN>
__global__ __launch_bounds__(256) void gemm_mfma(
    const void* __restrict__ Aptr, const unsigned short* __restrict__ BT,
    const float* __restrict__ bias, const float* __restrict__ gamma,
    const float* __restrict__ beta, void* __restrict__ Cptr, int M) {
    constexpr int BM = 64, N = NT * 16, NSTEP = K / 32;
    __shared__ unsigned short As[2][BM * 32];
    __shared__ unsigned short Bs[2][N * 32];
    const int tid = threadIdx.x;
    const int wave = tid >> 6, lane = tid & 63;
    const int l15 = lane & 15, quad = lane >> 4;
    const int row0 = blockIdx.x * BM;

    const int sr = tid >> 2, sc = tid & 3;
    const int sswz = sc ^ ((sr >> 2) & 3);
    const bool aok = (row0 + sr) < M;

    const float* A32p = (const float*)Aptr + (size_t)(row0 + sr) * K + sc * 8;
    const unsigned short* A16p = (const unsigned short*)Aptr + (size_t)(row0 + sr) * K + sc * 8;
    const unsigned short* B0p = BT + (size_t)sr * K + sc * 8;
    const unsigned short* B1p = BT + (size_t)(sr + 64) * K + sc * 8;

    float4 pa0, pa1;
    int4 pa16, pb0, pb1;
    if (A32) {
        pa0 = aok ? *(const float4*)(A32p) : make_float4(0.f, 0.f, 0.f, 0.f);
        pa1 = aok ? *(const float4*)(A32p + 4) : make_float4(0.f, 0.f, 0.f, 0.f);
    } else {
        pa16 = aok ? *(const int4*)(A16p) : make_int4(0, 0, 0, 0);
    }
    pb0 = *(const int4*)(B0p);
    if (NT == 8) pb1 = *(const int4*)(B1p);

    f32x4 acc[NT];
#pragma unroll
    for (int ni = 0; ni < NT; ni++) acc[ni] = (f32x4){0.f, 0.f, 0.f, 0.f};

    float bia[NT], gam[NT], bet[NT];
#pragma unroll
    for (int ni = 0; ni < NT; ni++) {
        bia[ni] = bias[ni * 16 + l15];
        if (LN) {
            gam[ni] = gamma[ni * 16 + l15];
            bet[ni] = beta[ni * 16 + l15];
        }
    }

    const int fswz = quad ^ ((l15 >> 2) & 3);
    const int aoff = (wave * 16 + l15) * 32 + fswz * 8;

    for (int step = 0; step < NSTEP; step++) {
        const int buf = step & 1;
        if (A32) {
            int4 w;
            w.x = (int)((unsigned int)bf16r(pa0.x) | ((unsigned int)bf16r(pa0.y) << 16));
            w.y = (int)((unsigned int)bf16r(pa0.z) | ((unsigned int)bf16r(pa0.w) << 16));
            w.z = (int)((unsigned int)bf16r(pa1.x) | ((unsigned int)bf16r(pa1.y) << 16));
            w.w = (int)((unsigned int)bf16r(pa1.z) | ((unsigned int)bf16r(pa1.w) << 16));
            *(int4*)&As[buf][sr * 32 + sswz * 8] = w;
        } else {
            *(int4*)&As[buf][sr * 32 + sswz * 8] = pa16;
        }
        *(int4*)&Bs[buf][sr * 32 + sswz * 8] = pb0;
        if (NT == 8) *(int4*)&Bs[buf][(sr + 64) * 32 + sswz * 8] = pb1;
        __syncthreads();
        if (step + 1 < NSTEP) {
            const int ko = (step + 1) * 32;
            if (A32) {
                pa0 = aok ? *(const float4*)(A32p + ko) : make_float4(0.f, 0.f, 0.f, 0.f);
                pa1 = aok ? *(const float4*)(A32p + ko + 4) : make_float4(0.f, 0.f, 0.f, 0.f);
            } else {
                pa16 = aok ? *(const int4*)(A16p + ko) : make_int4(0, 0, 0, 0);
            }
            pb0 = *(const int4*)(B0p + ko);
            if (NT == 8) pb1 = *(const int4*)(B1p + ko);
        }
        bf16x8 a = *(const bf16x8*)&As[buf][aoff];
#pragma unroll
        for (int ni = 0; ni < NT; ni++) {
            bf16x8 b = *(const bf16x8*)&Bs[buf][(ni * 16 + l15) * 32 + fswz * 8];
            acc[ni] = __builtin_amdgcn_mfma_f32_16x16x32_bf16(a, b, acc[ni], 0, 0, 0);
        }
    }

#pragma unroll
    for (int r = 0; r < 4; r++) {
        int grow = row0 + wave * 16 + quad * 4 + r;
        if (LN) {
            float g[NT];
            float s = 0.f, sq = 0.f;
#pragma unroll
            for (int ni = 0; ni < NT; ni++) {
                float v = gelu_exact(acc[ni][r] + bia[ni]);
                g[ni] = v;
                s += v;
                sq += v * v;
            }
#pragma unroll
            for (int m = 1; m < 16; m <<= 1) {
                s += __shfl_xor(s, m);
                sq += __shfl_xor(sq, m);
            }
            float mu = s * (1.0f / N);
            float var = sq * (1.0f / N) - mu * mu;
            float rs = rsqrtf(var + 1e-5f);
            if (grow < M) {
                unsigned short* C = (unsigned short*)Cptr;
#pragma unroll
                for (int ni = 0; ni < NT; ni++) {
                    float o = (g[ni] - mu) * rs * gam[ni] + bet[ni];
                    C[(size_t)grow * N + ni * 16 + l15] = bf16r(o);
                }
            }
        } else {
            if (grow < M) {
                float* C = (float*)Cptr;
#pragma unroll
                for (int ni = 0; ni < NT; ni++)
                    C[(size_t)grow * N + ni * 16 + l15] = acc[ni][r] + bia[ni];
            }
        }
    }
}

// ---------------- propagation: CSR gather on bf16 rows, one wave per node ----------------
__global__ __launch_bounds__(256) void sgc_gather_bf16(const unsigned short* __restrict__ hin,
                                                       unsigned short* __restrict__ hout,
                                                       const int* __restrict__ rowptr,
                                                       const int* __restrict__ eadj,
                                                       const float* __restrict__ dinv, int n) {
    int row = blockIdx.x * 4 + (threadIdx.x >> 6);
    int lane = threadIdx.x & 63;
    if (row >= n) return;
    float di = dinv[row];
    unsigned int u = *(const unsigned int*)(hin + (size_t)row * HID + lane * 2);
    float ax = bf16f((unsigned short)(u & 0xffff)) * di * di;
    float ay = bf16f((unsigned short)(u >> 16)) * di * di;
    int j = rowptr[row], end = rowptr[row + 1];
    for (; j + 7 < end; j += 8) {
        int s[8];
        float dv[8];
        unsigned int uu[8];
#pragma unroll
        for (int t = 0; t < 8; t++) s[t] = eadj[j + t];
#pragma unroll
        for (int t = 0; t < 8; t++) dv[t] = dinv[s[t]];
#pragma unroll
        for (int t = 0; t < 8; t++)
            uu[t] = *(const unsigned int*)(hin + (size_t)s[t] * HID + lane * 2);
#pragma unroll
        for (int t = 0; t < 8; t++) {
            float w = di * dv[t];
            ax += bf16f((unsigned short)(uu[t] & 0xffff)) * w;
            ay += bf16f((unsigned short)(uu[t] >> 16)) * w;
        }
    }
    for (; j + 1 < end; j += 2) {
        int s0 = eadj[j], s1 = eadj[j + 1];
        float w0 = di * dinv[s0], w1 = di * dinv[s1];
        unsigned int u0 = *(const unsigned int*)(hin + (size_t)s0 * HID + lane * 2);
        unsigned int u1 = *(const unsigned int*)(hin + (size_t)s1 * HID + lane * 2);
        ax += bf16f((unsigned short)(u0 & 0xffff)) * w0 + bf16f((unsigned short)(u1 & 0xffff)) * w1;
        ay += bf16f((unsigned short)(u0 >> 16)) * w0 + bf16f((unsigned short)(u1 >> 16)) * w1;
    }
    if (j < end) {
        int s0 = eadj[j];
        float w = di * dinv[s0];
        unsigned int u0 = *(const unsigned int*)(hin + (size_t)s0 * HID + lane * 2);
        ax += bf16f((unsigned short)(u0 & 0xffff)) * w;
        ay += bf16f((unsigned short)(u0 >> 16)) * w;
    }
    unsigned int o = (unsigned int)bf16r(ax) | ((unsigned int)bf16r(ay) << 16);
    *(unsigned int*)(hout + (size_t)row * HID + lane * 2) = o;
}

extern "C" void kernel_launch(void* const* d_in, const int* in_sizes, int n_in,
                              void* d_out, int out_size, void* d_ws, size_t ws_size,
                              hipStream_t stream) {
    const float* x   = (const float*)d_in[0];
    const int*   ei  = (const int*)d_in[1];
    const float* W1  = (const float*)d_in[2];
    const float* b1  = (const float*)d_in[3];
    const float* g1  = (const float*)d_in[4];
    const float* be1 = (const float*)d_in[5];
    const float* Wc  = (const float*)d_in[6];
    const float* bc  = (const float*)d_in[7];
    const float* g2  = (const float*)d_in[8];
    const float* be2 = (const float*)d_in[9];
    const float* W2  = (const float*)d_in[10];
    const float* b2  = (const float*)d_in[11];
    float* out = (float*)d_out;

    const int N = in_sizes[0] / IN_CH;  // 100000
    const int E = in_sizes[1] / 2;      // 1600000
    const int* src = ei;
    const int* dst = ei + E;

    char* ws = (char*)d_ws;
    size_t off = 0;
    auto alloc = [&](size_t bytes) {
        void* p = ws + off;
        off = (off + bytes + 255) & ~(size_t)255;
        return p;
    };
    float* dinv   = (float*)alloc((size_t)N * 4);
    int*   rowptr = (int*)alloc((size_t)(N + 1) * 4);
    int*   bcnt   = (int*)alloc((size_t)(NBUCK + 1) * 4);
    int*   bbase  = (int*)alloc((size_t)(NBUCK + 1) * 4);
    int*   bcur   = (int*)alloc((size_t)(NBUCK + 1) * 4);
    unsigned int* ebuf = (unsigned int*)alloc((size_t)E * 4);
    int*   eadj   = (int*)alloc((size_t)E * 4);
    unsigned short* W1T = (unsigned short*)alloc((size_t)HID * IN_CH * 2);
    unsigned short* WcT = (unsigned short*)alloc((size_t)HID * HID * 2);
    unsigned short* W2T = (unsigned short*)alloc((size_t)OUT_CH * HID * 2);
    unsigned short* hA  = (unsigned short*)alloc((size_t)N * HID * 2);
    unsigned short* hB  = (unsigned short*)alloc((size_t)N * HID * 2);

    const int B = 256;
    const int eblk16 = (E + 4095) / 4096;  // 391

    // bucketed CSR build (+ dinv, rowptr)
    bzero<<<1, 512, 0, stream>>>(bcnt);
    bhist<<<eblk16, B, 0, stream>>>(dst, bcnt, E);
    bscan<<<1, 512, 0, stream>>>(bcnt, bbase, bcur, rowptr, E);
    binA<<<eblk16, B, 0, stream>>>(src, dst, bcur, ebuf, E);
    binB<<<NBUCK, B, 0, stream>>>(ebuf, bbase, rowptr, eadj, dinv);

    // weight prep
    conv_t<<<(IN_CH * HID + 255) / 256, B, 0, stream>>>(W1, W1T, IN_CH, HID);
    conv_t<<<(HID * HID + 255) / 256, B, 0, stream>>>(Wc, WcT, HID, HID);
    conv_t<<<(HID * OUT_CH + 255) / 256, B, 0, stream>>>(W2, W2T, HID, OUT_CH);

    const int gblk = (N + 63) / 64;  // 1563
    // lin1 + gelu + LN -> hA (bf16)
    gemm_mfma<IN_CH, 8, true, true><<<gblk, B, 0, stream>>>(x, W1T, b1, g1, be1, hA, N);
    // hops: hA -> hB -> hA
    sgc_gather_bf16<<<(N + 3) / 4, B, 0, stream>>>(hA, hB, rowptr, eadj, dinv, N);
    sgc_gather_bf16<<<(N + 3) / 4, B, 0, stream>>>(hB, hA, rowptr, eadj, dinv, N);
    // Wc + gelu + LN -> hB (bf16)
    gemm_mfma<HID, 8, false, true><<<gblk, B, 0, stream>>>(hA, WcT, bc, g2, be2, hB, N);
    // W2 + bias -> out (fp32)
    gemm_mfma<HID, 4, false, false><<<gblk, B, 0, stream>>>(hB, W2T, b2, nullptr, nullptr, out, N);
}